// Round 12
// baseline (180.321 us; speedup 1.0000x reference)
//
#include <hip/hip_runtime.h>

#define N_NODES 50000
#define N_EDGES 800000
#define DIM 128
#define NCHUNK 3125     // N_NODES / 16
#define NBINS 782       // ceil(50000 / 64)
#define EPB 8192        // edges per binscat block
#define NSCAT 98        // ceil(800000 / 8192)
#define ZERO_INTS 50798 // deg (200,000 B) + binfill (3,128 B) = 203,192 B / 4

typedef _Float16 f16;
typedef _Float16 f16x4 __attribute__((ext_vector_type(4)));
typedef _Float16 f16x8 __attribute__((ext_vector_type(8)));
typedef float    f32x4 __attribute__((ext_vector_type(4)));
typedef float    f32x8 __attribute__((ext_vector_type(8)));

__device__ inline f32x8 cvt8(f16x8 v) { return __builtin_convertvector(v, f32x8); }

// ---------------- zero deg + binfill ----------------

__global__ __launch_bounds__(256) void k_zero(int* __restrict__ p) {
    int i = blockIdx.x * 256 + threadIdx.x;
    if (i < ZERO_INTS) p[i] = 0;
}

// ---------------- fused: edge count (even blocks) + x->f16 (odd blocks) + W prep (tail blocks) ----------------

__global__ __launch_bounds__(256) void k_prep(const int* __restrict__ dst, int* __restrict__ deg,
                                              const float* __restrict__ x, f16* __restrict__ xh,
                                              const float* __restrict__ W1l, const float* __restrict__ W1r,
                                              const float* __restrict__ W2l, const float* __restrict__ W2r,
                                              f16* __restrict__ Wf1, f16* __restrict__ Wf2) {
    int b = blockIdx.x;
    if (b < 6250) {
        int idx = (b >> 1) * 256 + threadIdx.x;      // 0..799,999 exactly
        if ((b & 1) == 0) {
            atomicAdd(&deg[dst[idx]], 1);
        } else {
            const float4* xs = (const float4*)x;
            float4 v0 = xs[(size_t)idx * 2];
            float4 v1 = xs[(size_t)idx * 2 + 1];
            f16x8 o;
            o[0]=(f16)v0.x; o[1]=(f16)v0.y; o[2]=(f16)v0.z; o[3]=(f16)v0.w;
            o[4]=(f16)v1.x; o[5]=(f16)v1.y; o[6]=(f16)v1.z; o[7]=(f16)v1.w;
            *(f16x8*)(xh + (size_t)idx * 8) = o;
        }
    } else {
        int t = (b - 6250) * 256 + threadIdx.x;      // 0..8191
        int layer = t >> 12;
        int nt = (t >> 9) & 7;
        int kk = (t >> 6) & 7;
        int lane = t & 63;
        int r = lane & 15, g = lane >> 4;
        int n = nt * 16 + r;
        const float* Wl_ = layer ? W2l : W1l;
        const float* Wr_ = layer ? W2r : W1r;
        f16x8 frag;
#pragma unroll
        for (int j = 0; j < 8; ++j) {
            int k = kk * 32 + g * 4 + (j & 3) + ((j >> 2) << 4);
            float f = (k < 128) ? Wl_[n * 128 + k] : Wr_[n * 128 + (k - 128)];
            frag[j] = (f16)f;
        }
        f16* dstp = (layer ? Wf2 : Wf1) + ((size_t)((nt * 8 + kk) * 64 + lane)) * 8;
        *(f16x8*)dstp = frag;
    }
}

// ---------------- per-bin edge counts: one wave per bin ----------------

__global__ __launch_bounds__(1024) void k_binsum(const int* __restrict__ deg, int* __restrict__ bincnt) {
    int t = threadIdx.x;
    int bin = blockIdx.x * 16 + (t >> 6);
    int node = (bin << 6) + (t & 63);
    int v = (bin < NBINS && node < N_NODES) ? deg[node] : 0;
#pragma unroll
    for (int off = 32; off; off >>= 1) v += __shfl_xor(v, off);
    if ((t & 63) == 0 && bin < NBINS) bincnt[bin] = v;
}

// ---------------- scan 782 bin counts -> binptr[783] ----------------

__global__ __launch_bounds__(1024) void k_binptr(const int* __restrict__ bincnt, int* __restrict__ binptr) {
    __shared__ int sm[1024];
    int t = threadIdx.x;
    int v = (t < NBINS) ? bincnt[t] : 0;
    sm[t] = v;
    __syncthreads();
    for (int off = 1; off < 1024; off <<= 1) {
        int u = (t >= off) ? sm[t - off] : 0;
        __syncthreads();
        sm[t] += u;
        __syncthreads();
    }
    if (t < NBINS) binptr[t + 1] = sm[t];
    if (t == 0) binptr[0] = 0;
}

// ---------------- binned scatter: block-aggregated LDS histogram, packed (src<<6|d&63) ----------------

__global__ __launch_bounds__(1024) void k_binscat(const int* __restrict__ src, const int* __restrict__ dst,
                                                  const int* __restrict__ binptr, int* __restrict__ binfill,
                                                  int* __restrict__ pairs) {
    __shared__ int hist[NBINS];
    __shared__ int base[NBINS];
    int t = threadIdx.x;
    for (int i = t; i < NBINS; i += 1024) hist[i] = 0;
    __syncthreads();
    int e0 = blockIdx.x * EPB;
    int mybin[8], myrank[8], mypack[8];
#pragma unroll
    for (int j = 0; j < 8; ++j) {
        int e = e0 + j * 1024 + t;
        if (e < N_EDGES) {
            int d = dst[e];
            int bin = d >> 6;
            mybin[j] = bin;
            mypack[j] = (src[e] << 6) | (d & 63);
            myrank[j] = atomicAdd(&hist[bin], 1);
        } else {
            mybin[j] = -1;
        }
    }
    __syncthreads();
    for (int i = t; i < NBINS; i += 1024) base[i] = atomicAdd(&binfill[i], hist[i]);
    __syncthreads();
#pragma unroll
    for (int j = 0; j < 8; ++j) {
        if (mybin[j] >= 0) {
            int bin = mybin[j];
            pairs[binptr[bin] + base[bin] + myrank[j]] = mypack[j];
        }
    }
}

// ---------------- fused bin-sort + mean aggregation: one block per bin ----------------
// Phase 1: counting-sort the bin's pairs into LDS-local CSR (64 LDS counters).
// Phase 2: 16-lane group per node, register f32x8 accumulation, 4 passes over 64 nodes.

__global__ __launch_bounds__(256) void k_binagg(const f16* __restrict__ X, const int* __restrict__ pairs,
                                                const int* __restrict__ binptr, const int* __restrict__ deg,
                                                f16* __restrict__ out) {
    __shared__ int lptr[65];
    __shared__ int lcnt[64];
    __shared__ int lsrt[2048];
    int bin = blockIdx.x;
    int t = threadIdx.x;
    int e0 = binptr[bin];
    int ne = binptr[bin + 1] - e0;
    int n0 = bin << 6;
    if (t < 64) {
        int node = n0 + t;
        int d = (node < N_NODES) ? deg[node] : 0;
        int v = d;
#pragma unroll
        for (int off = 1; off < 64; off <<= 1) {
            int u = __shfl_up(v, off);
            if (t >= off) v += u;
        }
        lptr[t + 1] = v;          // inclusive scan
        if (t == 0) lptr[0] = 0;
        lcnt[t] = v - d;          // exclusive = fill cursor
    }
    __syncthreads();
    for (int i = t; i < ne; i += 256) {
        int p = pairs[e0 + i];
        int slot = atomicAdd(&lcnt[p & 63], 1);
        lsrt[slot] = p >> 6;
    }
    __syncthreads();
    int lane = t & 15;
    const f16* __restrict__ base = X + lane * 8;
#pragma unroll
    for (int pass = 0; pass < 4; ++pass) {
        int m = pass * 16 + (t >> 4);
        int node = n0 + m;
        if (node >= N_NODES) continue;
        int beg = lptr[m], end = lptr[m + 1];
        f32x8 A0 = {0.f,0.f,0.f,0.f,0.f,0.f,0.f,0.f};
        f32x8 A1 = A0, A2 = A0, A3 = A0;
        int e = beg;
        for (; e + 4 <= end; e += 4) {
            int s0 = lsrt[e], s1 = lsrt[e + 1], s2 = lsrt[e + 2], s3 = lsrt[e + 3];
            A0 += cvt8(*(const f16x8*)(base + s0 * DIM));
            A1 += cvt8(*(const f16x8*)(base + s1 * DIM));
            A2 += cvt8(*(const f16x8*)(base + s2 * DIM));
            A3 += cvt8(*(const f16x8*)(base + s3 * DIM));
        }
        if (e < end)     A0 += cvt8(*(const f16x8*)(base + lsrt[e] * DIM));
        if (e + 1 < end) A1 += cvt8(*(const f16x8*)(base + lsrt[e + 1] * DIM));
        if (e + 2 < end) A2 += cvt8(*(const f16x8*)(base + lsrt[e + 2] * DIM));
        A0 = (A0 + A1) + (A2 + A3);
        float inv = 1.0f / fmaxf((float)(end - beg), 1.0f);
        f16x8 r;
#pragma unroll
        for (int j = 0; j < 8; ++j) r[j] = (f16)(A0[j] * inv);
        *(f16x8*)(out + (size_t)node * DIM + lane * 8) = r;
    }
}

// ---------------- MFMA dual GEMM: C = relu([agg|self] @ Wcat^T + b), all-f16 A ----------------

__global__ __launch_bounds__(512) void k_gemm(const f16* __restrict__ Agg, const f16* __restrict__ Xs,
                                              const f16* __restrict__ Wf, const float* __restrict__ bias,
                                              float* __restrict__ C, f16* __restrict__ Cb) {
    __shared__ uint4 Bsm[4096];   // 64 KB: [nt][kk][lane] 16B fragments
    int t = threadIdx.x;
    const uint4* wsrc = (const uint4*)Wf;
#pragma unroll
    for (int i = 0; i < 8; ++i) Bsm[t + i * 512] = wsrc[t + i * 512];
    __syncthreads();

    int wave = t >> 6, lane = t & 63;
    int chunk = blockIdx.x * 8 + wave;
    if (chunk >= NCHUNK) return;
    int r = lane & 15, g = lane >> 4;
    size_t row = (size_t)chunk * 16 + r;

    f32x4 acc[8];
#pragma unroll
    for (int nt = 0; nt < 8; ++nt) acc[nt] = (f32x4){0.f, 0.f, 0.f, 0.f};

#pragma unroll
    for (int kk = 0; kk < 8; ++kk) {
        const f16* arow = (kk < 4 ? Agg : Xs) + row * DIM + (kk & 3) * 32 + g * 4;
        f16x4 q0 = *(const f16x4*)(arow);
        f16x4 q1 = *(const f16x4*)(arow + 16);
        f16x8 a = __builtin_shufflevector(q0, q1, 0, 1, 2, 3, 4, 5, 6, 7);
#pragma unroll
        for (int nt = 0; nt < 8; ++nt) {
            f16x8 b = *(const f16x8*)&Bsm[(nt * 8 + kk) * 64 + lane];
            acc[nt] = __builtin_amdgcn_mfma_f32_16x16x32_f16(a, b, acc[nt], 0, 0, 0);
        }
    }
    size_t rbase = (size_t)chunk * 16 + g * 4;
#pragma unroll
    for (int nt = 0; nt < 8; ++nt) {
        int colc = nt * 16 + r;
        float bv = bias[colc];
#pragma unroll
        for (int q = 0; q < 4; ++q) {
            float v = fmaxf(acc[nt][q] + bv, 0.f);
            size_t idx = (rbase + q) * DIM + colc;
            if (C)  C[idx] = v;
            if (Cb) Cb[idx] = (f16)v;
        }
    }
}

// ---------------- launch ----------------

extern "C" void kernel_launch(void* const* d_in, const int* in_sizes, int n_in,
                              void* d_out, int out_size, void* d_ws, size_t ws_size,
                              hipStream_t stream) {
    const float* x   = (const float*)d_in[0];
    const int*   ei  = (const int*)d_in[1];
    const float* W1l = (const float*)d_in[2];
    const float* b1  = (const float*)d_in[3];
    const float* W1r = (const float*)d_in[4];
    const float* W2l = (const float*)d_in[5];
    const float* b2  = (const float*)d_in[6];
    const float* W2r = (const float*)d_in[7];
    float* out = (float*)d_out;

    const int* src = ei;
    const int* dst = ei + N_EDGES;

    char* ws = (char*)d_ws;
    int*  deg     = (int*)(ws + 0);              // 200,000 B
    int*  binfill = (int*)(ws + 200064);         // 3,128 B   (k_zero covers deg + binfill)
    int*  bincnt  = (int*)(ws + 203264);         // 3,128 B
    int*  binptr  = (int*)(ws + 206464);         // 3,132 B
    int*  pairs   = (int*)(ws + 403328);         // 3.2 MB (packed src<<6|dst&63, persistent)
    f16*  xh      = (f16*)(ws + 3603328);        // 12.8 MB (x f16, then h f16 after layer 1)
    f16*  aggh    = (f16*)(ws + 16403328);       // 12.8 MB
    f16*  Wf1     = (f16*)(ws + 29203328);       // 64 KB frag-order
    f16*  Wf2     = Wf1 + 32768;                 // 64 KB

    dim3 blk(256);
    k_zero<<<dim3((ZERO_INTS + 255) / 256), blk, 0, stream>>>((int*)ws);
    k_prep<<<dim3(6282), blk, 0, stream>>>(dst, deg, x, xh, W1l, W1r, W2l, W2r, Wf1, Wf2);
    k_binsum<<<dim3((NBINS + 15) / 16), dim3(1024), 0, stream>>>(deg, bincnt);
    k_binptr<<<dim3(1), dim3(1024), 0, stream>>>(bincnt, binptr);
    k_binscat<<<dim3(NSCAT), dim3(1024), 0, stream>>>(src, dst, binptr, binfill, pairs);

    dim3 grdG((NCHUNK + 7) / 8);

    // layer 1: h (f16 -> xh only) = relu(agg1 @ W1l^T + b1 + x @ W1r^T)   [self from xh f16]
    k_binagg<<<dim3(NBINS), blk, 0, stream>>>(xh, pairs, binptr, deg, aggh);
    k_gemm<<<grdG, dim3(512), 0, stream>>>(aggh, xh, Wf1, b1, (float*)nullptr, xh);

    // layer 2: out (f32) = relu(agg2 @ W2l^T + b2 + h @ W2r^T)            [self from xh f16]
    k_binagg<<<dim3(NBINS), blk, 0, stream>>>(xh, pairs, binptr, deg, aggh);
    k_gemm<<<grdG, dim3(512), 0, stream>>>(aggh, xh, Wf2, b2, out, (f16*)nullptr);
}

// Round 13
// 164.941 us; speedup vs baseline: 1.0932x; 1.0932x over previous
//
#include <hip/hip_runtime.h>

#define N_NODES 50000
#define N_EDGES 800000
#define DIM 128
#define NCHUNK 3125     // N_NODES / 16
#define SCAN_B 49       // ceil(50000 / 1024)
#define NBINS 782       // ceil(50000 / 64)
#define EPB 8192        // edges per binscat block
#define NSCAT 98        // ceil(800000 / 8192)
#define ZERO_INTS 50816 // 203,264 B / 4 : deg + bcnt + bcnt2 + binfill

typedef _Float16 f16;
typedef _Float16 f16x4 __attribute__((ext_vector_type(4)));
typedef _Float16 f16x8 __attribute__((ext_vector_type(8)));
typedef float    f32x4 __attribute__((ext_vector_type(4)));

__device__ inline f32x4 cvt4(f16x4 v) { return __builtin_convertvector(v, f32x4); }

__device__ inline int bucketof(int d) {
    if (d < 10) return 0;
    if (d < 13) return 1;
    if (d < 16) return 2;
    if (d < 19) return 3;
    if (d < 22) return 4;
    if (d < 26) return 5;
    if (d < 32) return 6;
    return 7;
}

// ---------------- zero counters ----------------

__global__ __launch_bounds__(256) void k_zero(int* __restrict__ p) {
    int i = blockIdx.x * 256 + threadIdx.x;
    if (i < ZERO_INTS) p[i] = 0;
}

// ---------------- fused: edge count + x -> f16 SLICED [4][N][32] + W prep ----------------

__global__ __launch_bounds__(256) void k_prep(const int* __restrict__ dst, int* __restrict__ deg,
                                              const float* __restrict__ x, f16* __restrict__ xs,
                                              const float* __restrict__ W1l, const float* __restrict__ W1r,
                                              const float* __restrict__ W2l, const float* __restrict__ W2r,
                                              f16* __restrict__ Wf1, f16* __restrict__ Wf2) {
    int b = blockIdx.x;
    if (b < 6250) {
        int idx = (b >> 1) * 256 + threadIdx.x;      // 0..799,999
        if ((b & 1) == 0) {
            atomicAdd(&deg[dst[idx]], 1);
        } else {
            int node = idx >> 4;
            int piece = idx & 15;
            int sl = piece >> 2;
            int sub = piece & 3;
            const float* xp = x + (size_t)node * DIM + sl * 32 + sub * 8;
            float4 v0 = *(const float4*)xp;
            float4 v1 = *(const float4*)(xp + 4);
            f16x8 o;
            o[0]=(f16)v0.x; o[1]=(f16)v0.y; o[2]=(f16)v0.z; o[3]=(f16)v0.w;
            o[4]=(f16)v1.x; o[5]=(f16)v1.y; o[6]=(f16)v1.z; o[7]=(f16)v1.w;
            *(f16x8*)(xs + ((size_t)sl * N_NODES + node) * 32 + sub * 8) = o;
        }
    } else {
        int t = (b - 6250) * 256 + threadIdx.x;      // 0..8191
        int layer = t >> 12;
        int nt = (t >> 9) & 7;
        int kk = (t >> 6) & 7;
        int lane = t & 63;
        int r = lane & 15, g = lane >> 4;
        int n = nt * 16 + r;
        const float* Wl_ = layer ? W2l : W1l;
        const float* Wr_ = layer ? W2r : W1r;
        f16x8 frag;
#pragma unroll
        for (int j = 0; j < 8; ++j) {
            int k = kk * 32 + g * 4 + (j & 3) + ((j >> 2) << 4);
            float f = (k < 128) ? Wl_[n * 128 + k] : Wr_[n * 128 + (k - 128)];
            frag[j] = (f16)f;
        }
        f16* dstp = (layer ? Wf2 : Wf1) + ((size_t)((nt * 8 + kk) * 64 + lane)) * 8;
        *(f16x8*)dstp = frag;
    }
}

// ---------------- scan phase A ----------------

__global__ __launch_bounds__(1024) void k_scanA(const int* __restrict__ deg, int* __restrict__ rowptr,
                                                int* __restrict__ bsum, int* __restrict__ bcnt) {
    __shared__ int sm[1024];
    __shared__ int h[8];
    int t = threadIdx.x;
    if (t < 8) h[t] = 0;
    int i = blockIdx.x * 1024 + t;
    int v = (i < N_NODES) ? deg[i] : 0;
    int orig = v;
    sm[t] = v;
    __syncthreads();
    if (i < N_NODES) atomicAdd(&h[bucketof(orig)], 1);
    for (int off = 1; off < 1024; off <<= 1) {
        int u = (t >= off) ? sm[t - off] : 0;
        __syncthreads();
        sm[t] += u;
        __syncthreads();
    }
    if (i < N_NODES) rowptr[i] = sm[t] - orig;
    if (t == 1023) bsum[blockIdx.x] = sm[t];
    if (t < 8 && h[t] > 0) atomicAdd(&bcnt[t], h[t]);
}

// ---------------- scan phase B ----------------

__global__ __launch_bounds__(64) void k_scanB(const int* __restrict__ bsum, int* __restrict__ boff,
                                              int* __restrict__ rowptr, const int* __restrict__ bcnt,
                                              int* __restrict__ bbase) {
    int t = threadIdx.x;
    int orig = (t < SCAN_B) ? bsum[t] : 0;
    int v = orig;
    for (int off = 1; off < 64; off <<= 1) {
        int u = __shfl_up(v, off);
        if (t >= off) v += u;
    }
    if (t < SCAN_B) boff[t] = v - orig;
    if (t == 63) rowptr[N_NODES] = N_EDGES;
    if (t == 0) {
        int r = 0;
#pragma unroll
        for (int b = 0; b < 8; ++b) { bbase[b] = r; r += bcnt[b]; }
    }
}

// ---------------- scan phase C ----------------

__global__ __launch_bounds__(1024) void k_scanC(int* __restrict__ rowptr, const int* __restrict__ boff,
                                                const int* __restrict__ deg, const int* __restrict__ bbase,
                                                int* __restrict__ bcnt2, int* __restrict__ order) {
    __shared__ int h[8];
    __shared__ int hb[8];
    int t = threadIdx.x;
    if (t < 8) h[t] = 0;
    __syncthreads();
    int i = blockIdx.x * 1024 + t;
    int b = 0, rank = 0;
    bool act = (i < N_NODES);
    if (act) {
        rowptr[i] += boff[blockIdx.x];
        b = bucketof(deg[i]);
        rank = atomicAdd(&h[b], 1);
    }
    __syncthreads();
    if (t < 8) hb[t] = atomicAdd(&bcnt2[t], h[t]);
    __syncthreads();
    if (act) order[bbase[b] + hb[b] + rank] = i;
}

// ---------------- binned scatter pass A ----------------

__global__ __launch_bounds__(1024) void k_binscat(const int* __restrict__ src, const int* __restrict__ dst,
                                                  const int* __restrict__ rowptr, int* __restrict__ binfill,
                                                  int* __restrict__ pairs) {
    __shared__ int hist[NBINS];
    __shared__ int base[NBINS];
    int t = threadIdx.x;
    for (int i = t; i < NBINS; i += 1024) hist[i] = 0;
    __syncthreads();
    int e0 = blockIdx.x * EPB;
    int mybin[8], myrank[8], mypack[8];
#pragma unroll
    for (int j = 0; j < 8; ++j) {
        int e = e0 + j * 1024 + t;
        if (e < N_EDGES) {
            int d = dst[e];
            int bin = d >> 6;
            mybin[j] = bin;
            mypack[j] = (src[e] << 6) | (d & 63);
            myrank[j] = atomicAdd(&hist[bin], 1);
        } else {
            mybin[j] = -1;
        }
    }
    __syncthreads();
    for (int i = t; i < NBINS; i += 1024) base[i] = atomicAdd(&binfill[i], hist[i]);
    __syncthreads();
#pragma unroll
    for (int j = 0; j < 8; ++j) {
        if (mybin[j] >= 0) {
            int bin = mybin[j];
            pairs[rowptr[bin << 6] + base[bin] + myrank[j]] = mypack[j];
        }
    }
}

// ---------------- binned scatter pass B: global srt (built once, read 8x) ----------------

__global__ __launch_bounds__(256) void k_binsolve(const int* __restrict__ pairs, const int* __restrict__ rowptr,
                                                  int* __restrict__ srt) {
    __shared__ int lfill[64];
    int bin = blockIdx.x;
    int nstart = bin << 6;
    int nend = min(N_NODES, nstart + 64);
    int t = threadIdx.x;
    if (t < 64) lfill[t] = (nstart + t < N_NODES) ? rowptr[nstart + t] : 0;
    __syncthreads();
    int estart = rowptr[nstart];
    int eend = rowptr[nend];
    for (int i = estart + t; i < eend; i += 256) {
        int p = pairs[i];
        int slot = atomicAdd(&lfill[p & 63], 1);
        srt[slot] = p >> 6;
    }
}

// ---------------- mean aggregation: 4-slice XCD-resident. block b -> slice b&3 (3.2 MB, L2-fit) ----------------
// 8-lane group per node (64 B = 1 line per row-load), 32 nodes/block, degree-binned order, unroll 4.

__global__ __launch_bounds__(256) void k_aggregate(const f16* __restrict__ Xs, const int* __restrict__ rowptr,
                                                   const int* __restrict__ srt, const int* __restrict__ order,
                                                   f16* __restrict__ out) {
    int bid = blockIdx.x;
    int sl = bid & 3;
    int gid = (bid >> 2) * 32 + (threadIdx.x >> 3);
    if (gid >= N_NODES) return;
    int w = order[gid];
    int lane8 = threadIdx.x & 7;
    const f16* __restrict__ base = Xs + (size_t)sl * N_NODES * 32 + lane8 * 4;
    int beg = rowptr[w], end = rowptr[w + 1];
    f32x4 A0 = {0.f, 0.f, 0.f, 0.f};
    f32x4 A1 = A0, A2 = A0, A3 = A0;
    int e = beg;
    for (; e + 4 <= end; e += 4) {
        int s0 = srt[e], s1 = srt[e + 1], s2 = srt[e + 2], s3 = srt[e + 3];
        A0 += cvt4(*(const f16x4*)(base + (size_t)s0 * 32));
        A1 += cvt4(*(const f16x4*)(base + (size_t)s1 * 32));
        A2 += cvt4(*(const f16x4*)(base + (size_t)s2 * 32));
        A3 += cvt4(*(const f16x4*)(base + (size_t)s3 * 32));
    }
    if (e < end)     A0 += cvt4(*(const f16x4*)(base + (size_t)srt[e] * 32));
    if (e + 1 < end) A1 += cvt4(*(const f16x4*)(base + (size_t)srt[e + 1] * 32));
    if (e + 2 < end) A2 += cvt4(*(const f16x4*)(base + (size_t)srt[e + 2] * 32));
    A0 = (A0 + A1) + (A2 + A3);
    float inv = 1.0f / fmaxf((float)(end - beg), 1.0f);
    f16x4 r;
#pragma unroll
    for (int j = 0; j < 4; ++j) r[j] = (f16)(A0[j] * inv);
    *(f16x4*)(out + ((size_t)sl * N_NODES + w) * 32 + lane8 * 4) = r;
}

// ---------------- MFMA dual GEMM: sliced A operands; C f32 [node][128]; Cb f16 sliced ----------------

__global__ __launch_bounds__(512) void k_gemm(const f16* __restrict__ Agg, const f16* __restrict__ Xs,
                                              const f16* __restrict__ Wf, const float* __restrict__ bias,
                                              float* __restrict__ C, f16* __restrict__ Cb) {
    __shared__ uint4 Bsm[4096];   // 64 KB: [nt][kk][lane] 16B fragments
    int t = threadIdx.x;
    const uint4* wsrc = (const uint4*)Wf;
#pragma unroll
    for (int i = 0; i < 8; ++i) Bsm[t + i * 512] = wsrc[t + i * 512];
    __syncthreads();

    int wave = t >> 6, lane = t & 63;
    int chunk = blockIdx.x * 8 + wave;
    if (chunk >= NCHUNK) return;
    int r = lane & 15, g = lane >> 4;
    size_t row = (size_t)chunk * 16 + r;

    f32x4 acc[8];
#pragma unroll
    for (int nt = 0; nt < 8; ++nt) acc[nt] = (f32x4){0.f, 0.f, 0.f, 0.f};

#pragma unroll
    for (int kk = 0; kk < 8; ++kk) {
        const f16* arow = (kk < 4 ? Agg : Xs) + ((size_t)(kk & 3) * N_NODES + row) * 32 + g * 4;
        f16x4 q0 = *(const f16x4*)(arow);
        f16x4 q1 = *(const f16x4*)(arow + 16);
        f16x8 a = __builtin_shufflevector(q0, q1, 0, 1, 2, 3, 4, 5, 6, 7);
#pragma unroll
        for (int nt = 0; nt < 8; ++nt) {
            f16x8 b = *(const f16x8*)&Bsm[(nt * 8 + kk) * 64 + lane];
            acc[nt] = __builtin_amdgcn_mfma_f32_16x16x32_f16(a, b, acc[nt], 0, 0, 0);
        }
    }
    size_t rbase = (size_t)chunk * 16 + g * 4;
#pragma unroll
    for (int nt = 0; nt < 8; ++nt) {
        int colc = nt * 16 + r;
        float bv = bias[colc];
        int csl = nt >> 1;
        int cwi = colc & 31;
#pragma unroll
        for (int q = 0; q < 4; ++q) {
            float v = fmaxf(acc[nt][q] + bv, 0.f);
            size_t node = rbase + q;
            if (C)  C[node * DIM + colc] = v;
            if (Cb) Cb[((size_t)csl * N_NODES + node) * 32 + cwi] = (f16)v;
        }
    }
}

// ---------------- launch ----------------

extern "C" void kernel_launch(void* const* d_in, const int* in_sizes, int n_in,
                              void* d_out, int out_size, void* d_ws, size_t ws_size,
                              hipStream_t stream) {
    const float* x   = (const float*)d_in[0];
    const int*   ei  = (const int*)d_in[1];
    const float* W1l = (const float*)d_in[2];
    const float* b1  = (const float*)d_in[3];
    const float* W1r = (const float*)d_in[4];
    const float* W2l = (const float*)d_in[5];
    const float* b2  = (const float*)d_in[6];
    const float* W2r = (const float*)d_in[7];
    float* out = (float*)d_out;

    const int* src = ei;
    const int* dst = ei + N_EDGES;

    char* ws = (char*)d_ws;
    int*  deg     = (int*)(ws + 0);              // 200,000 B
    int*  bcnt    = (int*)(ws + 200064);         // 32 B
    int*  bcnt2   = (int*)(ws + 200096);         // 32 B
    int*  binfill = (int*)(ws + 200128);         // 3,128 B   (k_zero covers through here)
    int*  rowptr  = (int*)(ws + 203264);         // 200,004 B
    int*  srt     = (int*)(ws + 403328);         // 3,200,000 B
    f16*  xh      = (f16*)(ws + 3603328);        // 12.8 MB sliced [4][N][32] (x f16, then h f16)
    f16*  aggh    = (f16*)(ws + 16403328);       // 12.8 MB sliced agg
    int*  pairs   = (int*)(ws + 16403328);       // 3.2 MB (overlaps aggh; dead before agg runs)
    f16*  Wf1     = (f16*)(ws + 29203328);       // 64 KB frag-order
    f16*  Wf2     = Wf1 + 32768;                 // 64 KB
    int*  bsum    = (int*)(ws + 29334400);       // 256 B
    int*  boff    = (int*)(ws + 29334656);       // 256 B
    int*  bbase   = (int*)(ws + 29334912);       // 64 B
    int*  order   = (int*)(ws + 29334976);       // 200,000 B

    dim3 blk(256);
    k_zero<<<dim3((ZERO_INTS + 255) / 256), blk, 0, stream>>>((int*)ws);
    k_prep<<<dim3(6282), blk, 0, stream>>>(dst, deg, x, xh, W1l, W1r, W2l, W2r, Wf1, Wf2);
    k_scanA<<<dim3(SCAN_B), dim3(1024), 0, stream>>>(deg, rowptr, bsum, bcnt);
    k_scanB<<<dim3(1), dim3(64), 0, stream>>>(bsum, boff, rowptr, bcnt, bbase);
    k_scanC<<<dim3(SCAN_B), dim3(1024), 0, stream>>>(rowptr, boff, deg, bbase, bcnt2, order);
    k_binscat<<<dim3(NSCAT), dim3(1024), 0, stream>>>(src, dst, rowptr, binfill, pairs);
    k_binsolve<<<dim3(NBINS), blk, 0, stream>>>(pairs, rowptr, srt);

    dim3 grdA(4 * ((N_NODES + 31) / 32));        // 6252 blocks: slice = bid&3, chunk = bid>>2
    dim3 grdG((NCHUNK + 7) / 8);

    // layer 1: h (f16 sliced -> xh) = relu(agg1 @ W1l^T + b1 + x @ W1r^T)
    k_aggregate<<<grdA, blk, 0, stream>>>(xh, rowptr, srt, order, aggh);
    k_gemm<<<grdG, dim3(512), 0, stream>>>(aggh, xh, Wf1, b1, (float*)nullptr, xh);

    // layer 2: out (f32) = relu(agg2 @ W2l^T + b2 + h @ W2r^T)
    k_aggregate<<<grdA, blk, 0, stream>>>(xh, rowptr, srt, order, aggh);
    k_gemm<<<grdG, dim3(512), 0, stream>>>(aggh, xh, Wf2, b2, out, (f16*)nullptr);
}

// Round 14
// 163.230 us; speedup vs baseline: 1.1047x; 1.0105x over previous
//
#include <hip/hip_runtime.h>

#define N_NODES 50000
#define N_EDGES 800000
#define DIM 128
#define NCHUNK 3125     // N_NODES / 16
#define NBINS 782       // ceil(50000 / 64)
#define CAP 2048        // per-bin pair capacity (max bin load ~1150 for Poisson(1023))
#define EPB 8192        // edges per binscat block
#define NSCAT 98        // ceil(800000 / 8192)

typedef _Float16 f16;
typedef _Float16 f16x4 __attribute__((ext_vector_type(4)));
typedef _Float16 f16x8 __attribute__((ext_vector_type(8)));
typedef float    f32x4 __attribute__((ext_vector_type(4)));
typedef unsigned short u16;

__device__ inline f32x4 cvt4(f16x4 v) { return __builtin_convertvector(v, f32x4); }

__device__ inline int bucketof(int d) {
    if (d < 10) return 0;
    if (d < 13) return 1;
    if (d < 16) return 2;
    if (d < 19) return 3;
    if (d < 22) return 4;
    if (d < 26) return 5;
    if (d < 32) return 6;
    return 7;
}

// ---------------- zero binfill (782 ints) ----------------

__global__ __launch_bounds__(256) void k_zero(int* __restrict__ p) {
    int i = blockIdx.x * 256 + threadIdx.x;
    if (i < NBINS) p[i] = 0;
}

// ---------------- fused: x -> f16 SLICED [4][N][32] (blocks 0..3124) + W prep (tail) ----------------

__global__ __launch_bounds__(256) void k_prep(const float* __restrict__ x, f16* __restrict__ xs,
                                              const float* __restrict__ W1l, const float* __restrict__ W1r,
                                              const float* __restrict__ W2l, const float* __restrict__ W2r,
                                              f16* __restrict__ Wf1, f16* __restrict__ Wf2) {
    int b = blockIdx.x;
    if (b < 3125) {
        int idx = b * 256 + threadIdx.x;             // 0..799,999 (f16x8 pieces)
        int node = idx >> 4;
        int piece = idx & 15;
        int sl = piece >> 2;
        int sub = piece & 3;
        const float* xp = x + (size_t)node * DIM + sl * 32 + sub * 8;
        float4 v0 = *(const float4*)xp;
        float4 v1 = *(const float4*)(xp + 4);
        f16x8 o;
        o[0]=(f16)v0.x; o[1]=(f16)v0.y; o[2]=(f16)v0.z; o[3]=(f16)v0.w;
        o[4]=(f16)v1.x; o[5]=(f16)v1.y; o[6]=(f16)v1.z; o[7]=(f16)v1.w;
        *(f16x8*)(xs + ((size_t)sl * N_NODES + node) * 32 + sub * 8) = o;
    } else {
        int t = (b - 3125) * 256 + threadIdx.x;      // 0..8191
        int layer = t >> 12;
        int nt = (t >> 9) & 7;
        int kk = (t >> 6) & 7;
        int lane = t & 63;
        int r = lane & 15, g = lane >> 4;
        int n = nt * 16 + r;
        const float* Wl_ = layer ? W2l : W1l;
        const float* Wr_ = layer ? W2r : W1r;
        f16x8 frag;
#pragma unroll
        for (int j = 0; j < 8; ++j) {
            int k = kk * 32 + g * 4 + (j & 3) + ((j >> 2) << 4);
            float f = (k < 128) ? Wl_[n * 128 + k] : Wr_[n * 128 + (k - 128)];
            frag[j] = (f16)f;
        }
        f16* dstp = (layer ? Wf2 : Wf1) + ((size_t)((nt * 8 + kk) * 64 + lane)) * 8;
        *(f16x8*)dstp = frag;
    }
}

// ---------------- binned scatter: block LDS histogram -> fixed-capacity bin regions ----------------

__global__ __launch_bounds__(1024) void k_binscat(const int* __restrict__ src, const int* __restrict__ dst,
                                                  int* __restrict__ binfill, int* __restrict__ pairs) {
    __shared__ int hist[NBINS];
    __shared__ int base[NBINS];
    int t = threadIdx.x;
    for (int i = t; i < NBINS; i += 1024) hist[i] = 0;
    __syncthreads();
    int e0 = blockIdx.x * EPB;
    int mybin[8], myrank[8], mypack[8];
#pragma unroll
    for (int j = 0; j < 8; ++j) {
        int e = e0 + j * 1024 + t;
        if (e < N_EDGES) {
            int d = dst[e];
            int bin = d >> 6;
            mybin[j] = bin;
            mypack[j] = (src[e] << 6) | (d & 63);
            myrank[j] = atomicAdd(&hist[bin], 1);
        } else {
            mybin[j] = -1;
        }
    }
    __syncthreads();
    for (int i = t; i < NBINS; i += 1024) base[i] = atomicAdd(&binfill[i], hist[i]);
    __syncthreads();
#pragma unroll
    for (int j = 0; j < 8; ++j) {
        if (mybin[j] >= 0) {
            int bin = mybin[j];
            int pos = base[bin] + myrank[j];
            if (pos < CAP) pairs[bin * CAP + pos] = mypack[j];
        }
    }
}

// ---------------- bin solve: per-node degree/rowbeg/srt(u16)/local degree-sorted order ----------------

__global__ __launch_bounds__(256) void k_binsolve(const int* __restrict__ pairs, const int* __restrict__ binfill,
                                                  u16* __restrict__ srt, int* __restrict__ rowbeg,
                                                  int* __restrict__ degA, int* __restrict__ order) {
    __shared__ int lcnt[64];
    __shared__ int lptr[64];
    __shared__ int lcur[64];
    __shared__ int h8[8];
    __shared__ int bb[8];
    int bin = blockIdx.x;
    int t = threadIdx.x;
    int p0 = bin * CAP;
    int cnt = min(binfill[bin], CAP);
    if (t < 64) lcnt[t] = 0;
    if (t < 8) h8[t] = 0;
    __syncthreads();
    for (int i = t; i < cnt; i += 256) atomicAdd(&lcnt[pairs[p0 + i] & 63], 1);
    __syncthreads();
    if (t < 64) {                          // wave 0: exclusive scan of 64 degrees
        int d = lcnt[t];
        int v = d;
#pragma unroll
        for (int off = 1; off < 64; off <<= 1) {
            int u = __shfl_up(v, off);
            if (t >= off) v += u;
        }
        lptr[t] = v - d;
        lcur[t] = v - d;
    }
    __syncthreads();
    for (int i = t; i < cnt; i += 256) {   // counting-sort into srt
        int p = pairs[p0 + i];
        int slot = atomicAdd(&lcur[p & 63], 1);
        srt[p0 + slot] = (u16)(p >> 6);
    }
    int node = bin * 64 + t;
    bool act = (t < 64) && (node < N_NODES);
    int b = 0, r8 = 0;
    if (act) {
        rowbeg[node] = p0 + lptr[t];
        degA[node] = lcnt[t];
        b = bucketof(lcnt[t]);
        r8 = atomicAdd(&h8[b], 1);
    }
    __syncthreads();
    if (t == 0) {
        int r = 0;
#pragma unroll
        for (int i = 0; i < 8; ++i) { bb[i] = r; r += h8[i]; }
    }
    __syncthreads();
    if (act) order[bin * 64 + bb[b] + r8] = node;
}

// ---------------- mean aggregation: 4-slice XCD-resident, 8-lane group/node, u16 srt ----------------

__global__ __launch_bounds__(256) void k_aggregate(const f16* __restrict__ Xs, const int* __restrict__ rowbeg,
                                                   const int* __restrict__ degA, const u16* __restrict__ srt,
                                                   const int* __restrict__ order, f16* __restrict__ out) {
    int bid = blockIdx.x;
    int sl = bid & 3;
    int gid = (bid >> 2) * 32 + (threadIdx.x >> 3);
    if (gid >= N_NODES) return;
    int w = order[gid];
    int lane8 = threadIdx.x & 7;
    const f16* __restrict__ base = Xs + (size_t)sl * N_NODES * 32 + lane8 * 4;
    int beg = rowbeg[w];
    int d = degA[w];
    int end = beg + d;
    f32x4 A0 = {0.f, 0.f, 0.f, 0.f};
    f32x4 A1 = A0, A2 = A0, A3 = A0;
    int e = beg;
    for (; e + 4 <= end; e += 4) {
        int s0 = __builtin_nontemporal_load(srt + e);
        int s1 = __builtin_nontemporal_load(srt + e + 1);
        int s2 = __builtin_nontemporal_load(srt + e + 2);
        int s3 = __builtin_nontemporal_load(srt + e + 3);
        A0 += cvt4(*(const f16x4*)(base + (size_t)s0 * 32));
        A1 += cvt4(*(const f16x4*)(base + (size_t)s1 * 32));
        A2 += cvt4(*(const f16x4*)(base + (size_t)s2 * 32));
        A3 += cvt4(*(const f16x4*)(base + (size_t)s3 * 32));
    }
    if (e < end)     A0 += cvt4(*(const f16x4*)(base + (size_t)__builtin_nontemporal_load(srt + e) * 32));
    if (e + 1 < end) A1 += cvt4(*(const f16x4*)(base + (size_t)__builtin_nontemporal_load(srt + e + 1) * 32));
    if (e + 2 < end) A2 += cvt4(*(const f16x4*)(base + (size_t)__builtin_nontemporal_load(srt + e + 2) * 32));
    A0 = (A0 + A1) + (A2 + A3);
    float inv = 1.0f / fmaxf((float)d, 1.0f);
    f16x4 r;
#pragma unroll
    for (int j = 0; j < 4; ++j) r[j] = (f16)(A0[j] * inv);
    *(f16x4*)(out + ((size_t)sl * N_NODES + w) * 32 + lane8 * 4) = r;
}

// ---------------- MFMA dual GEMM: sliced A operands; C f32 [node][128]; Cb f16 sliced ----------------

__global__ __launch_bounds__(512) void k_gemm(const f16* __restrict__ Agg, const f16* __restrict__ Xs,
                                              const f16* __restrict__ Wf, const float* __restrict__ bias,
                                              float* __restrict__ C, f16* __restrict__ Cb) {
    __shared__ uint4 Bsm[4096];   // 64 KB: [nt][kk][lane] 16B fragments
    int t = threadIdx.x;
    const uint4* wsrc = (const uint4*)Wf;
#pragma unroll
    for (int i = 0; i < 8; ++i) Bsm[t + i * 512] = wsrc[t + i * 512];
    __syncthreads();

    int wave = t >> 6, lane = t & 63;
    int chunk = blockIdx.x * 8 + wave;
    if (chunk >= NCHUNK) return;
    int r = lane & 15, g = lane >> 4;
    size_t row = (size_t)chunk * 16 + r;

    f32x4 acc[8];
#pragma unroll
    for (int nt = 0; nt < 8; ++nt) acc[nt] = (f32x4){0.f, 0.f, 0.f, 0.f};

#pragma unroll
    for (int kk = 0; kk < 8; ++kk) {
        const f16* arow = (kk < 4 ? Agg : Xs) + ((size_t)(kk & 3) * N_NODES + row) * 32 + g * 4;
        f16x4 q0 = *(const f16x4*)(arow);
        f16x4 q1 = *(const f16x4*)(arow + 16);
        f16x8 a = __builtin_shufflevector(q0, q1, 0, 1, 2, 3, 4, 5, 6, 7);
#pragma unroll
        for (int nt = 0; nt < 8; ++nt) {
            f16x8 b = *(const f16x8*)&Bsm[(nt * 8 + kk) * 64 + lane];
            acc[nt] = __builtin_amdgcn_mfma_f32_16x16x32_f16(a, b, acc[nt], 0, 0, 0);
        }
    }
    size_t rbase = (size_t)chunk * 16 + g * 4;
#pragma unroll
    for (int nt = 0; nt < 8; ++nt) {
        int colc = nt * 16 + r;
        float bv = bias[colc];
        int csl = nt >> 1;
        int cwi = colc & 31;
#pragma unroll
        for (int q = 0; q < 4; ++q) {
            float v = fmaxf(acc[nt][q] + bv, 0.f);
            size_t node = rbase + q;
            if (C)  C[node * DIM + colc] = v;
            if (Cb) Cb[((size_t)csl * N_NODES + node) * 32 + cwi] = (f16)v;
        }
    }
}

// ---------------- launch ----------------

extern "C" void kernel_launch(void* const* d_in, const int* in_sizes, int n_in,
                              void* d_out, int out_size, void* d_ws, size_t ws_size,
                              hipStream_t stream) {
    const float* x   = (const float*)d_in[0];
    const int*   ei  = (const int*)d_in[1];
    const float* W1l = (const float*)d_in[2];
    const float* b1  = (const float*)d_in[3];
    const float* W1r = (const float*)d_in[4];
    const float* W2l = (const float*)d_in[5];
    const float* b2  = (const float*)d_in[6];
    const float* W2r = (const float*)d_in[7];
    float* out = (float*)d_out;

    const int* src = ei;
    const int* dst = ei + N_EDGES;

    char* ws = (char*)d_ws;
    int*  binfill = (int*)(ws + 0);              // 3,128 B (zeroed)
    int*  degA    = (int*)(ws + 3200);           // 200,000 B
    int*  rowbeg  = (int*)(ws + 203264);         // 200,000 B
    int*  order   = (int*)(ws + 403264);         // 200,000 B
    u16*  srt     = (u16*)(ws + 603264);         // 3,203,072 B (782*2048*2)
    f16*  xh      = (f16*)(ws + 3806336);        // 12.8 MB sliced [4][N][32] (x f16, then h f16)
    f16*  aggh    = (f16*)(ws + 16606336);       // 12.8 MB sliced agg
    int*  pairs   = (int*)(ws + 16606336);       // 6,406,144 B (overlaps aggh; dead before agg)
    f16*  Wf1     = (f16*)(ws + 29406336);       // 64 KB frag-order
    f16*  Wf2     = Wf1 + 32768;                 // 64 KB -> ends ~29.54 MB

    dim3 blk(256);
    k_zero<<<dim3(4), blk, 0, stream>>>(binfill);
    k_prep<<<dim3(3157), blk, 0, stream>>>(x, xh, W1l, W1r, W2l, W2r, Wf1, Wf2);
    k_binscat<<<dim3(NSCAT), dim3(1024), 0, stream>>>(src, dst, binfill, pairs);
    k_binsolve<<<dim3(NBINS), blk, 0, stream>>>(pairs, binfill, srt, rowbeg, degA, order);

    dim3 grdA(4 * ((N_NODES + 31) / 32));        // 6252 blocks: slice = bid&3
    dim3 grdG((NCHUNK + 7) / 8);

    // layer 1: h (f16 sliced -> xh) = relu(agg1 @ W1l^T + b1 + x @ W1r^T)
    k_aggregate<<<grdA, blk, 0, stream>>>(xh, rowbeg, degA, srt, order, aggh);
    k_gemm<<<grdG, dim3(512), 0, stream>>>(aggh, xh, Wf1, b1, (float*)nullptr, xh);

    // layer 2: out (f32) = relu(agg2 @ W2l^T + b2 + h @ W2r^T)
    k_aggregate<<<grdA, blk, 0, stream>>>(xh, rowbeg, degA, srt, order, aggh);
    k_gemm<<<grdG, dim3(512), 0, stream>>>(aggh, xh, Wf2, b2, out, (f16*)nullptr);
}

// Round 15
// 159.344 us; speedup vs baseline: 1.1316x; 1.0244x over previous
//
#include <hip/hip_runtime.h>

#define N_NODES 50000
#define N_EDGES 800000
#define DIM 128
#define NCHUNK 3125     // N_NODES / 16
#define NBINS 782       // ceil(50000 / 64)
#define CAP 2048        // per-bin pair capacity
#define EPB 8192        // edges per binscat block
#define NSCAT 98        // ceil(800000 / 8192)

typedef _Float16 f16;
typedef _Float16 f16x4 __attribute__((ext_vector_type(4)));
typedef _Float16 f16x8 __attribute__((ext_vector_type(8)));
typedef float    f32x4 __attribute__((ext_vector_type(4)));
typedef unsigned short u16;

__device__ inline f32x4 cvt4(f16x4 v) { return __builtin_convertvector(v, f32x4); }

__device__ inline int bucketof(int d) {
    if (d < 10) return 0;
    if (d < 13) return 1;
    if (d < 16) return 2;
    if (d < 19) return 3;
    if (d < 22) return 4;
    if (d < 26) return 5;
    if (d < 32) return 6;
    return 7;
}

// ---------------- zero binfill ----------------

__global__ __launch_bounds__(256) void k_zero(int* __restrict__ p) {
    int i = blockIdx.x * 256 + threadIdx.x;
    if (i < NBINS) p[i] = 0;
}

// ---------------- fused: x -> f16 SLICED [4][N][32] + W prep ----------------

__global__ __launch_bounds__(256) void k_prep(const float* __restrict__ x, f16* __restrict__ xs,
                                              const float* __restrict__ W1l, const float* __restrict__ W1r,
                                              const float* __restrict__ W2l, const float* __restrict__ W2r,
                                              f16* __restrict__ Wf1, f16* __restrict__ Wf2) {
    int b = blockIdx.x;
    if (b < 3125) {
        int idx = b * 256 + threadIdx.x;             // 0..799,999 (f16x8 pieces)
        int node = idx >> 4;
        int piece = idx & 15;
        int sl = piece >> 2;
        int sub = piece & 3;
        const float* xp = x + (size_t)node * DIM + sl * 32 + sub * 8;
        float4 v0 = *(const float4*)xp;
        float4 v1 = *(const float4*)(xp + 4);
        f16x8 o;
        o[0]=(f16)v0.x; o[1]=(f16)v0.y; o[2]=(f16)v0.z; o[3]=(f16)v0.w;
        o[4]=(f16)v1.x; o[5]=(f16)v1.y; o[6]=(f16)v1.z; o[7]=(f16)v1.w;
        *(f16x8*)(xs + ((size_t)sl * N_NODES + node) * 32 + sub * 8) = o;
    } else {
        int t = (b - 3125) * 256 + threadIdx.x;      // 0..8191
        int layer = t >> 12;
        int nt = (t >> 9) & 7;
        int kk = (t >> 6) & 7;
        int lane = t & 63;
        int r = lane & 15, g = lane >> 4;
        int n = nt * 16 + r;
        const float* Wl_ = layer ? W2l : W1l;
        const float* Wr_ = layer ? W2r : W1r;
        f16x8 frag;
#pragma unroll
        for (int j = 0; j < 8; ++j) {
            int k = kk * 32 + g * 4 + (j & 3) + ((j >> 2) << 4);
            float f = (k < 128) ? Wl_[n * 128 + k] : Wr_[n * 128 + (k - 128)];
            frag[j] = (f16)f;
        }
        f16* dstp = (layer ? Wf2 : Wf1) + ((size_t)((nt * 8 + kk) * 64 + lane)) * 8;
        *(f16x8*)dstp = frag;
    }
}

// ---------------- binned scatter ----------------

__global__ __launch_bounds__(1024) void k_binscat(const int* __restrict__ src, const int* __restrict__ dst,
                                                  int* __restrict__ binfill, int* __restrict__ pairs) {
    __shared__ int hist[NBINS];
    __shared__ int base[NBINS];
    int t = threadIdx.x;
    for (int i = t; i < NBINS; i += 1024) hist[i] = 0;
    __syncthreads();
    int e0 = blockIdx.x * EPB;
    int mybin[8], myrank[8], mypack[8];
#pragma unroll
    for (int j = 0; j < 8; ++j) {
        int e = e0 + j * 1024 + t;
        if (e < N_EDGES) {
            int d = dst[e];
            int bin = d >> 6;
            mybin[j] = bin;
            mypack[j] = (src[e] << 6) | (d & 63);
            myrank[j] = atomicAdd(&hist[bin], 1);
        } else {
            mybin[j] = -1;
        }
    }
    __syncthreads();
    for (int i = t; i < NBINS; i += 1024) base[i] = atomicAdd(&binfill[i], hist[i]);
    __syncthreads();
#pragma unroll
    for (int j = 0; j < 8; ++j) {
        if (mybin[j] >= 0) {
            int bin = mybin[j];
            int pos = base[bin] + myrank[j];
            if (pos < CAP) pairs[bin * CAP + pos] = mypack[j];
        }
    }
}

// ---------------- bin solve ----------------

__global__ __launch_bounds__(256) void k_binsolve(const int* __restrict__ pairs, const int* __restrict__ binfill,
                                                  u16* __restrict__ srt, int* __restrict__ rowbeg,
                                                  int* __restrict__ degA, int* __restrict__ order) {
    __shared__ int lcnt[64];
    __shared__ int lptr[64];
    __shared__ int lcur[64];
    __shared__ int h8[8];
    __shared__ int bb[8];
    int bin = blockIdx.x;
    int t = threadIdx.x;
    int p0 = bin * CAP;
    int cnt = min(binfill[bin], CAP);
    if (t < 64) lcnt[t] = 0;
    if (t < 8) h8[t] = 0;
    __syncthreads();
    for (int i = t; i < cnt; i += 256) atomicAdd(&lcnt[pairs[p0 + i] & 63], 1);
    __syncthreads();
    if (t < 64) {
        int d = lcnt[t];
        int v = d;
#pragma unroll
        for (int off = 1; off < 64; off <<= 1) {
            int u = __shfl_up(v, off);
            if (t >= off) v += u;
        }
        lptr[t] = v - d;
        lcur[t] = v - d;
    }
    __syncthreads();
    for (int i = t; i < cnt; i += 256) {
        int p = pairs[p0 + i];
        int slot = atomicAdd(&lcur[p & 63], 1);
        srt[p0 + slot] = (u16)(p >> 6);
    }
    int node = bin * 64 + t;
    bool act = (t < 64) && (node < N_NODES);
    int b = 0, r8 = 0;
    if (act) {
        rowbeg[node] = p0 + lptr[t];
        degA[node] = lcnt[t];
        b = bucketof(lcnt[t]);
        r8 = atomicAdd(&h8[b], 1);
    }
    __syncthreads();
    if (t == 0) {
        int r = 0;
#pragma unroll
        for (int i = 0; i < 8; ++i) { bb[i] = r; r += h8[i]; }
    }
    __syncthreads();
    if (act) order[bin * 64 + bb[b] + r8] = node;
}

// ---------------- mean aggregation: 1024-thread blocks (2 blocks/CU = 32 waves), unroll 8 ----------------
// 4-slice XCD layout, 8-lane group per node, u16 srt.

__global__ __launch_bounds__(1024) void k_aggregate(const f16* __restrict__ Xs, const int* __restrict__ rowbeg,
                                                    const int* __restrict__ degA, const u16* __restrict__ srt,
                                                    const int* __restrict__ order, f16* __restrict__ out) {
    int bid = blockIdx.x;
    int sl = bid & 3;
    int gid = (bid >> 2) * 128 + (threadIdx.x >> 3);
    if (gid >= N_NODES) return;
    int w = order[gid];
    int lane8 = threadIdx.x & 7;
    const f16* __restrict__ base = Xs + (size_t)sl * N_NODES * 32 + lane8 * 4;
    int beg = rowbeg[w];
    int d = degA[w];
    int end = beg + d;
    f32x4 A0 = {0.f, 0.f, 0.f, 0.f};
    f32x4 A1 = A0, A2 = A0, A3 = A0, A4 = A0, A5 = A0, A6 = A0, A7 = A0;
    int e = beg;
    for (; e + 8 <= end; e += 8) {           // 8 independent row loads in flight per group
        int s0 = __builtin_nontemporal_load(srt + e);
        int s1 = __builtin_nontemporal_load(srt + e + 1);
        int s2 = __builtin_nontemporal_load(srt + e + 2);
        int s3 = __builtin_nontemporal_load(srt + e + 3);
        int s4 = __builtin_nontemporal_load(srt + e + 4);
        int s5 = __builtin_nontemporal_load(srt + e + 5);
        int s6 = __builtin_nontemporal_load(srt + e + 6);
        int s7 = __builtin_nontemporal_load(srt + e + 7);
        f16x4 v0 = *(const f16x4*)(base + (size_t)s0 * 32);
        f16x4 v1 = *(const f16x4*)(base + (size_t)s1 * 32);
        f16x4 v2 = *(const f16x4*)(base + (size_t)s2 * 32);
        f16x4 v3 = *(const f16x4*)(base + (size_t)s3 * 32);
        f16x4 v4 = *(const f16x4*)(base + (size_t)s4 * 32);
        f16x4 v5 = *(const f16x4*)(base + (size_t)s5 * 32);
        f16x4 v6 = *(const f16x4*)(base + (size_t)s6 * 32);
        f16x4 v7 = *(const f16x4*)(base + (size_t)s7 * 32);
        A0 += cvt4(v0); A1 += cvt4(v1); A2 += cvt4(v2); A3 += cvt4(v3);
        A4 += cvt4(v4); A5 += cvt4(v5); A6 += cvt4(v6); A7 += cvt4(v7);
    }
    if (e + 4 <= end) {
        int s0 = __builtin_nontemporal_load(srt + e);
        int s1 = __builtin_nontemporal_load(srt + e + 1);
        int s2 = __builtin_nontemporal_load(srt + e + 2);
        int s3 = __builtin_nontemporal_load(srt + e + 3);
        A0 += cvt4(*(const f16x4*)(base + (size_t)s0 * 32));
        A1 += cvt4(*(const f16x4*)(base + (size_t)s1 * 32));
        A2 += cvt4(*(const f16x4*)(base + (size_t)s2 * 32));
        A3 += cvt4(*(const f16x4*)(base + (size_t)s3 * 32));
        e += 4;
    }
    if (e < end)     A4 += cvt4(*(const f16x4*)(base + (size_t)__builtin_nontemporal_load(srt + e) * 32));
    if (e + 1 < end) A5 += cvt4(*(const f16x4*)(base + (size_t)__builtin_nontemporal_load(srt + e + 1) * 32));
    if (e + 2 < end) A6 += cvt4(*(const f16x4*)(base + (size_t)__builtin_nontemporal_load(srt + e + 2) * 32));
    A0 = ((A0 + A1) + (A2 + A3)) + ((A4 + A5) + (A6 + A7));
    float inv = 1.0f / fmaxf((float)d, 1.0f);
    f16x4 r;
#pragma unroll
    for (int j = 0; j < 4; ++j) r[j] = (f16)(A0[j] * inv);
    *(f16x4*)(out + ((size_t)sl * N_NODES + w) * 32 + lane8 * 4) = r;
}

// ---------------- MFMA dual GEMM ----------------

__global__ __launch_bounds__(512) void k_gemm(const f16* __restrict__ Agg, const f16* __restrict__ Xs,
                                              const f16* __restrict__ Wf, const float* __restrict__ bias,
                                              float* __restrict__ C, f16* __restrict__ Cb) {
    __shared__ uint4 Bsm[4096];   // 64 KB
    int t = threadIdx.x;
    const uint4* wsrc = (const uint4*)Wf;
#pragma unroll
    for (int i = 0; i < 8; ++i) Bsm[t + i * 512] = wsrc[t + i * 512];
    __syncthreads();

    int wave = t >> 6, lane = t & 63;
    int chunk = blockIdx.x * 8 + wave;
    if (chunk >= NCHUNK) return;
    int r = lane & 15, g = lane >> 4;
    size_t row = (size_t)chunk * 16 + r;

    f32x4 acc[8];
#pragma unroll
    for (int nt = 0; nt < 8; ++nt) acc[nt] = (f32x4){0.f, 0.f, 0.f, 0.f};

#pragma unroll
    for (int kk = 0; kk < 8; ++kk) {
        const f16* arow = (kk < 4 ? Agg : Xs) + ((size_t)(kk & 3) * N_NODES + row) * 32 + g * 4;
        f16x4 q0 = *(const f16x4*)(arow);
        f16x4 q1 = *(const f16x4*)(arow + 16);
        f16x8 a = __builtin_shufflevector(q0, q1, 0, 1, 2, 3, 4, 5, 6, 7);
#pragma unroll
        for (int nt = 0; nt < 8; ++nt) {
            f16x8 b = *(const f16x8*)&Bsm[(nt * 8 + kk) * 64 + lane];
            acc[nt] = __builtin_amdgcn_mfma_f32_16x16x32_f16(a, b, acc[nt], 0, 0, 0);
        }
    }
    size_t rbase = (size_t)chunk * 16 + g * 4;
#pragma unroll
    for (int nt = 0; nt < 8; ++nt) {
        int colc = nt * 16 + r;
        float bv = bias[colc];
        int csl = nt >> 1;
        int cwi = colc & 31;
#pragma unroll
        for (int q = 0; q < 4; ++q) {
            float v = fmaxf(acc[nt][q] + bv, 0.f);
            size_t node = rbase + q;
            if (C)  C[node * DIM + colc] = v;
            if (Cb) Cb[((size_t)csl * N_NODES + node) * 32 + cwi] = (f16)v;
        }
    }
}

// ---------------- launch ----------------

extern "C" void kernel_launch(void* const* d_in, const int* in_sizes, int n_in,
                              void* d_out, int out_size, void* d_ws, size_t ws_size,
                              hipStream_t stream) {
    const float* x   = (const float*)d_in[0];
    const int*   ei  = (const int*)d_in[1];
    const float* W1l = (const float*)d_in[2];
    const float* b1  = (const float*)d_in[3];
    const float* W1r = (const float*)d_in[4];
    const float* W2l = (const float*)d_in[5];
    const float* b2  = (const float*)d_in[6];
    const float* W2r = (const float*)d_in[7];
    float* out = (float*)d_out;

    const int* src = ei;
    const int* dst = ei + N_EDGES;

    char* ws = (char*)d_ws;
    int*  binfill = (int*)(ws + 0);              // 3,128 B (zeroed)
    int*  degA    = (int*)(ws + 3200);           // 200,000 B
    int*  rowbeg  = (int*)(ws + 203264);         // 200,000 B
    int*  order   = (int*)(ws + 403264);         // 200,000 B
    u16*  srt     = (u16*)(ws + 603264);         // 3,203,072 B
    f16*  xh      = (f16*)(ws + 3806336);        // 12.8 MB sliced [4][N][32]
    f16*  aggh    = (f16*)(ws + 16606336);       // 12.8 MB sliced agg
    int*  pairs   = (int*)(ws + 16606336);       // 6.4 MB (overlaps aggh)
    f16*  Wf1     = (f16*)(ws + 29406336);       // 64 KB
    f16*  Wf2     = Wf1 + 32768;                 // 64 KB

    dim3 blk(256);
    k_zero<<<dim3(4), blk, 0, stream>>>(binfill);
    k_prep<<<dim3(3157), blk, 0, stream>>>(x, xh, W1l, W1r, W2l, W2r, Wf1, Wf2);
    k_binscat<<<dim3(NSCAT), dim3(1024), 0, stream>>>(src, dst, binfill, pairs);
    k_binsolve<<<dim3(NBINS), blk, 0, stream>>>(pairs, binfill, srt, rowbeg, degA, order);

    dim3 grdA(4 * ((N_NODES + 127) / 128));      // 1564 blocks x 1024 thr: slice = bid&3
    dim3 grdG((NCHUNK + 7) / 8);

    // layer 1: h (f16 sliced -> xh) = relu(agg1 @ W1l^T + b1 + x @ W1r^T)
    k_aggregate<<<grdA, dim3(1024), 0, stream>>>(xh, rowbeg, degA, srt, order, aggh);
    k_gemm<<<grdG, dim3(512), 0, stream>>>(aggh, xh, Wf1, b1, (float*)nullptr, xh);

    // layer 2: out (f32) = relu(agg2 @ W2l^T + b2 + h @ W2r^T)
    k_aggregate<<<grdA, dim3(1024), 0, stream>>>(xh, rowbeg, degA, srt, order, aggh);
    k_gemm<<<grdG, dim3(512), 0, stream>>>(aggh, xh, Wf2, b2, out, (f16*)nullptr);
}

// Round 16
// 128.528 us; speedup vs baseline: 1.4030x; 1.2398x over previous
//
#include <hip/hip_runtime.h>

#define N_NODES 50000
#define N_EDGES 800000
#define DIM 128
#define NBINS 782      // ceil(50000 / 64)
#define CAP 2048       // per-bin pair capacity
#define EPB 8192       // edges per binscat block
#define NSCAT 98       // ceil(800000 / 8192)

typedef _Float16 f16;
typedef _Float16 f16x4 __attribute__((ext_vector_type(4)));
typedef _Float16 f16x8 __attribute__((ext_vector_type(8)));
typedef float    f32x4 __attribute__((ext_vector_type(4)));
typedef float    f32x8 __attribute__((ext_vector_type(8)));
typedef unsigned short u16;

__device__ inline f32x8 cvt8(f16x8 v) { return __builtin_convertvector(v, f32x8); }

__device__ inline int bucketof(int d) {
    if (d < 10) return 0;
    if (d < 13) return 1;
    if (d < 16) return 2;
    if (d < 19) return 3;
    if (d < 22) return 4;
    if (d < 26) return 5;
    if (d < 32) return 6;
    return 7;
}

// ---------------- prep: x->f16 linear (blocks 0..3124) + W frag-order (3125..3156) + zero binfill (3157) ----------------

__global__ __launch_bounds__(256) void k_prep(const float* __restrict__ x, f16* __restrict__ xh,
                                              const float* __restrict__ W1l, const float* __restrict__ W1r,
                                              const float* __restrict__ W2l, const float* __restrict__ W2r,
                                              f16* __restrict__ Wf1, f16* __restrict__ Wf2,
                                              int* __restrict__ binfill) {
    int b = blockIdx.x;
    if (b < 3125) {
        int idx = b * 256 + threadIdx.x;             // 0..799,999 : one f16x8 piece each
        const float* xp = x + (size_t)idx * 8;
        float4 v0 = *(const float4*)xp;
        float4 v1 = *(const float4*)(xp + 4);
        f16x8 o;
        o[0]=(f16)v0.x; o[1]=(f16)v0.y; o[2]=(f16)v0.z; o[3]=(f16)v0.w;
        o[4]=(f16)v1.x; o[5]=(f16)v1.y; o[6]=(f16)v1.z; o[7]=(f16)v1.w;
        *(f16x8*)(xh + (size_t)idx * 8) = o;
    } else if (b < 3157) {
        int t = (b - 3125) * 256 + threadIdx.x;      // 0..8191
        int layer = t >> 12;
        int nt = (t >> 9) & 7;
        int kk = (t >> 6) & 7;
        int lane = t & 63;
        int r = lane & 15, g = lane >> 4;
        int n = nt * 16 + r;
        const float* Wl_ = layer ? W2l : W1l;
        const float* Wr_ = layer ? W2r : W1r;
        f16x8 frag;
#pragma unroll
        for (int j = 0; j < 8; ++j) {
            int k = kk * 32 + g * 4 + (j & 3) + ((j >> 2) << 4);
            float f = (k < 128) ? Wl_[n * 128 + k] : Wr_[n * 128 + (k - 128)];
            frag[j] = (f16)f;
        }
        f16* dstp = (layer ? Wf2 : Wf1) + ((size_t)((nt * 8 + kk) * 64 + lane)) * 8;
        *(f16x8*)dstp = frag;
    } else {
        for (int i = threadIdx.x; i < NBINS; i += 256) binfill[i] = 0;
    }
}

// ---------------- binned scatter: block LDS histogram -> fixed-capacity bin regions ----------------

__global__ __launch_bounds__(1024) void k_binscat(const int* __restrict__ src, const int* __restrict__ dst,
                                                  int* __restrict__ binfill, int* __restrict__ pairs) {
    __shared__ int hist[NBINS];
    __shared__ int base[NBINS];
    int t = threadIdx.x;
    for (int i = t; i < NBINS; i += 1024) hist[i] = 0;
    __syncthreads();
    int e0 = blockIdx.x * EPB;
    int mybin[8], myrank[8], mypack[8];
#pragma unroll
    for (int j = 0; j < 8; ++j) {
        int e = e0 + j * 1024 + t;
        if (e < N_EDGES) {
            int d = dst[e];
            int bin = d >> 6;
            mybin[j] = bin;
            mypack[j] = (src[e] << 6) | (d & 63);
            myrank[j] = atomicAdd(&hist[bin], 1);
        } else {
            mybin[j] = -1;
        }
    }
    __syncthreads();
    for (int i = t; i < NBINS; i += 1024) base[i] = atomicAdd(&binfill[i], hist[i]);
    __syncthreads();
#pragma unroll
    for (int j = 0; j < 8; ++j) {
        if (mybin[j] >= 0) {
            int bin = mybin[j];
            int pos = base[bin] + myrank[j];
            if (pos < CAP) pairs[bin * CAP + pos] = mypack[j];
        }
    }
}

// ---------------- bin solve: per-node degree/rowbeg/srt(u16)/bin-local degree-sorted order ----------------

__global__ __launch_bounds__(256) void k_binsolve(const int* __restrict__ pairs, const int* __restrict__ binfill,
                                                  u16* __restrict__ srt, int* __restrict__ rowbeg,
                                                  int* __restrict__ degA, int* __restrict__ order) {
    __shared__ int lcnt[64];
    __shared__ int lptr[64];
    __shared__ int lcur[64];
    __shared__ int h8[8];
    __shared__ int bb[8];
    int bin = blockIdx.x;
    int t = threadIdx.x;
    int p0 = bin * CAP;
    int cnt = min(binfill[bin], CAP);
    if (t < 64) lcnt[t] = 0;
    if (t < 8) h8[t] = 0;
    __syncthreads();
    for (int i = t; i < cnt; i += 256) atomicAdd(&lcnt[pairs[p0 + i] & 63], 1);
    __syncthreads();
    if (t < 64) {
        int d = lcnt[t];
        int v = d;
#pragma unroll
        for (int off = 1; off < 64; off <<= 1) {
            int u = __shfl_up(v, off);
            if (t >= off) v += u;
        }
        lptr[t] = v - d;
        lcur[t] = v - d;
    }
    __syncthreads();
    for (int i = t; i < cnt; i += 256) {
        int p = pairs[p0 + i];
        int slot = atomicAdd(&lcur[p & 63], 1);
        srt[p0 + slot] = (u16)(p >> 6);
    }
    int node = bin * 64 + t;
    bool act = (t < 64) && (node < N_NODES);
    int b = 0, r8 = 0;
    if (act) {
        rowbeg[node] = p0 + lptr[t];
        degA[node] = lcnt[t];
        b = bucketof(lcnt[t]);
        r8 = atomicAdd(&h8[b], 1);
    }
    __syncthreads();
    if (t == 0) {
        int r = 0;
#pragma unroll
        for (int i = 0; i < 8; ++i) { bb[i] = r; r += h8[i]; }
    }
    __syncthreads();
    if (act) order[bin * 64 + bb[b] + r8] = node;
}

// ---------------- FUSED layer: aggregate (bin of 64 nodes -> LDS) + dual MFMA GEMM ----------------
// Phase A: 16 groups x 16 lanes gather full 256B rows, degree-ranked, mean -> LDS agg[64][136].
// Phase B: wave w MFMAs nodes n0+w*16..+16: A from LDS (agg) / global (self), W frags from L2.

__global__ __launch_bounds__(256) void k_fused(const f16* __restrict__ Xh, const u16* __restrict__ srt,
                                               const int* __restrict__ rowbeg, const int* __restrict__ degA,
                                               const int* __restrict__ order, const f16* __restrict__ Wf,
                                               const float* __restrict__ bias,
                                               float* __restrict__ C, f16* __restrict__ Cb) {
    __shared__ f16 agg[64][136];   // +8 pad: 2-way-max bank aliasing on reads
    int bin = blockIdx.x;
    int n0 = bin << 6;
    int t = threadIdx.x;
    int g = t >> 4, l16 = t & 15;
    int nvalid = N_NODES - n0; if (nvalid > 64) nvalid = 64;
    const f16* __restrict__ base = Xh + l16 * 8;

#pragma unroll
    for (int p = 0; p < 4; ++p) {
        int rank = p * 16 + g;     // adjacent groups in a wave -> adjacent ranks -> similar degree
        if (rank < nvalid) {
            int node = order[n0 + rank];
            int m = node - n0;
            int beg = rowbeg[node];
            int d = degA[node];
            int end = beg + d;
            f32x8 A0 = {0.f,0.f,0.f,0.f,0.f,0.f,0.f,0.f};
            f32x8 A1 = A0, A2 = A0, A3 = A0;
            int e = beg;
            for (; e + 4 <= end; e += 4) {
                int s0 = __builtin_nontemporal_load(srt + e);
                int s1 = __builtin_nontemporal_load(srt + e + 1);
                int s2 = __builtin_nontemporal_load(srt + e + 2);
                int s3 = __builtin_nontemporal_load(srt + e + 3);
                A0 += cvt8(*(const f16x8*)(base + (size_t)s0 * DIM));
                A1 += cvt8(*(const f16x8*)(base + (size_t)s1 * DIM));
                A2 += cvt8(*(const f16x8*)(base + (size_t)s2 * DIM));
                A3 += cvt8(*(const f16x8*)(base + (size_t)s3 * DIM));
            }
            if (e < end)     A0 += cvt8(*(const f16x8*)(base + (size_t)__builtin_nontemporal_load(srt + e) * DIM));
            if (e + 1 < end) A1 += cvt8(*(const f16x8*)(base + (size_t)__builtin_nontemporal_load(srt + e + 1) * DIM));
            if (e + 2 < end) A2 += cvt8(*(const f16x8*)(base + (size_t)__builtin_nontemporal_load(srt + e + 2) * DIM));
            A0 = (A0 + A1) + (A2 + A3);
            float inv = 1.0f / fmaxf((float)d, 1.0f);
            f16x8 r;
#pragma unroll
            for (int j = 0; j < 8; ++j) r[j] = (f16)(A0[j] * inv);
            *(f16x8*)&agg[m][l16 * 8] = r;
        }
    }
    __syncthreads();

    int wave = t >> 6, lane = t & 63;
    int r = lane & 15, gg = lane >> 4;
    int rowloc = wave * 16 + r;
    size_t grow = (size_t)n0 + rowloc;
    size_t growc = (grow < N_NODES) ? grow : (N_NODES - 1);   // clamp OOB self reads (tail bin)

    f32x4 acc[8];
#pragma unroll
    for (int nt = 0; nt < 8; ++nt) acc[nt] = (f32x4){0.f, 0.f, 0.f, 0.f};

#pragma unroll
    for (int kk = 0; kk < 8; ++kk) {
        f16x8 a;
        if (kk < 4) {
            f16x4 q0 = *(const f16x4*)&agg[rowloc][kk * 32 + gg * 4];
            f16x4 q1 = *(const f16x4*)&agg[rowloc][kk * 32 + gg * 4 + 16];
            a = __builtin_shufflevector(q0, q1, 0, 1, 2, 3, 4, 5, 6, 7);
        } else {
            const f16* arow = Xh + growc * DIM + (kk - 4) * 32 + gg * 4;
            f16x4 q0 = *(const f16x4*)(arow);
            f16x4 q1 = *(const f16x4*)(arow + 16);
            a = __builtin_shufflevector(q0, q1, 0, 1, 2, 3, 4, 5, 6, 7);
        }
#pragma unroll
        for (int nt = 0; nt < 8; ++nt) {
            f16x8 b = *(const f16x8*)(Wf + ((size_t)((nt * 8 + kk) * 64 + lane)) * 8);
            acc[nt] = __builtin_amdgcn_mfma_f32_16x16x32_f16(a, b, acc[nt], 0, 0, 0);
        }
    }
    size_t rbase = (size_t)n0 + wave * 16 + gg * 4;
#pragma unroll
    for (int nt = 0; nt < 8; ++nt) {
        int colc = nt * 16 + r;
        float bv = bias[colc];
#pragma unroll
        for (int q = 0; q < 4; ++q) {
            size_t node = rbase + q;
            if (node < N_NODES) {
                float v = fmaxf(acc[nt][q] + bv, 0.f);
                if (C)  C[node * DIM + colc] = v;
                if (Cb) Cb[node * DIM + colc] = (f16)v;
            }
        }
    }
}

// ---------------- launch ----------------

extern "C" void kernel_launch(void* const* d_in, const int* in_sizes, int n_in,
                              void* d_out, int out_size, void* d_ws, size_t ws_size,
                              hipStream_t stream) {
    const float* x   = (const float*)d_in[0];
    const int*   ei  = (const int*)d_in[1];
    const float* W1l = (const float*)d_in[2];
    const float* b1  = (const float*)d_in[3];
    const float* W1r = (const float*)d_in[4];
    const float* W2l = (const float*)d_in[5];
    const float* b2  = (const float*)d_in[6];
    const float* W2r = (const float*)d_in[7];
    float* out = (float*)d_out;

    const int* src = ei;
    const int* dst = ei + N_EDGES;

    char* ws = (char*)d_ws;
    int*  binfill = (int*)(ws + 0);              // 3,128 B (zeroed by prep block 3157)
    int*  degA    = (int*)(ws + 3200);           // 200,000 B
    int*  rowbeg  = (int*)(ws + 203264);         // 200,000 B
    int*  order   = (int*)(ws + 403264);         // 200,000 B
    u16*  srt     = (u16*)(ws + 603264);         // 3,203,072 B -> ends 3,806,336
    f16*  xh      = (f16*)(ws + 3806336);        // 12.8 MB x f16 -> ends 16,606,336
    f16*  hh      = (f16*)(ws + 16606336);       // 12.8 MB h f16 -> ends 29,406,336
    int*  pairs   = (int*)(ws + 16606336);       // 6.4 MB, overlaps hh (dead after binsolve)
    f16*  Wf1     = (f16*)(ws + 29406336);       // 64 KB frag-order
    f16*  Wf2     = Wf1 + 32768;                 // 64 KB -> ends ~29.54 MB

    dim3 blk(256);
    k_prep<<<dim3(3158), blk, 0, stream>>>(x, xh, W1l, W1r, W2l, W2r, Wf1, Wf2, binfill);
    k_binscat<<<dim3(NSCAT), dim3(1024), 0, stream>>>(src, dst, binfill, pairs);
    k_binsolve<<<dim3(NBINS), blk, 0, stream>>>(pairs, binfill, srt, rowbeg, degA, order);

    // layer 1: h (f16 -> hh) = relu(agg(x) @ W1l^T + b1 + x @ W1r^T)
    k_fused<<<dim3(NBINS), blk, 0, stream>>>(xh, srt, rowbeg, degA, order, Wf1, b1, (float*)nullptr, hh);

    // layer 2: out (f32) = relu(agg(h) @ W2l^T + b2 + h @ W2r^T)
    k_fused<<<dim3(NBINS), blk, 0, stream>>>(hh, srt, rowbeg, degA, order, Wf2, b2, out, (f16*)nullptr);
}

// Round 17
// 120.252 us; speedup vs baseline: 1.4995x; 1.0688x over previous
//
#include <hip/hip_runtime.h>

#define N_NODES 50000
#define N_EDGES 800000
#define DIM 128
#define NBINS 782      // ceil(50000 / 64)
#define CAP 2048       // per-bin pair capacity
#define EPB 8192       // edges per binscat block
#define NSCAT 98       // ceil(800000 / 8192)

typedef _Float16 f16;
typedef _Float16 f16x4 __attribute__((ext_vector_type(4)));
typedef _Float16 f16x8 __attribute__((ext_vector_type(8)));
typedef float    f32x2 __attribute__((ext_vector_type(2)));
typedef float    f32x4 __attribute__((ext_vector_type(4)));
typedef unsigned short u16;
typedef unsigned char  u8;

__device__ inline int bucketof(int d) {
    if (d < 10) return 0;
    if (d < 13) return 1;
    if (d < 16) return 2;
    if (d < 19) return 3;
    if (d < 22) return 4;
    if (d < 26) return 5;
    if (d < 32) return 6;
    return 7;
}

// ---------------- prep: x->fp8 (blocks 0..3124) + W frag-order (3125..3156) + zero binfill (3157) ----------------

__global__ __launch_bounds__(256) void k_prep(const float* __restrict__ x, u8* __restrict__ x8,
                                              const float* __restrict__ W1l, const float* __restrict__ W1r,
                                              const float* __restrict__ W2l, const float* __restrict__ W2r,
                                              f16* __restrict__ Wf1, f16* __restrict__ Wf2,
                                              int* __restrict__ binfill) {
    int b = blockIdx.x;
    if (b < 3125) {
        int idx = b * 256 + threadIdx.x;             // 0..799,999 : 8 f32 -> 8 fp8 each
        const float* xp = x + (size_t)idx * 8;
        float4 v0 = *(const float4*)xp;
        float4 v1 = *(const float4*)(xp + 4);
        int r0 = 0, r1 = 0;
        r0 = __builtin_amdgcn_cvt_pk_fp8_f32(v0.x, v0.y, r0, false);
        r0 = __builtin_amdgcn_cvt_pk_fp8_f32(v0.z, v0.w, r0, true);
        r1 = __builtin_amdgcn_cvt_pk_fp8_f32(v1.x, v1.y, r1, false);
        r1 = __builtin_amdgcn_cvt_pk_fp8_f32(v1.z, v1.w, r1, true);
        uint2 w; w.x = (unsigned)r0; w.y = (unsigned)r1;
        *(uint2*)(x8 + (size_t)idx * 8) = w;
    } else if (b < 3157) {
        int t = (b - 3125) * 256 + threadIdx.x;      // 0..8191
        int layer = t >> 12;
        int nt = (t >> 9) & 7;
        int kk = (t >> 6) & 7;
        int lane = t & 63;
        int r = lane & 15, g = lane >> 4;
        int n = nt * 16 + r;
        const float* Wl_ = layer ? W2l : W1l;
        const float* Wr_ = layer ? W2r : W1r;
        f16x8 frag;
#pragma unroll
        for (int j = 0; j < 8; ++j) {
            int k = kk * 32 + g * 4 + (j & 3) + ((j >> 2) << 4);
            float f = (k < 128) ? Wl_[n * 128 + k] : Wr_[n * 128 + (k - 128)];
            frag[j] = (f16)f;
        }
        f16* dstp = (layer ? Wf2 : Wf1) + ((size_t)((nt * 8 + kk) * 64 + lane)) * 8;
        *(f16x8*)dstp = frag;
    } else {
        for (int i = threadIdx.x; i < NBINS; i += 256) binfill[i] = 0;
    }
}

// ---------------- binned scatter ----------------

__global__ __launch_bounds__(1024) void k_binscat(const int* __restrict__ src, const int* __restrict__ dst,
                                                  int* __restrict__ binfill, int* __restrict__ pairs) {
    __shared__ int hist[NBINS];
    __shared__ int base[NBINS];
    int t = threadIdx.x;
    for (int i = t; i < NBINS; i += 1024) hist[i] = 0;
    __syncthreads();
    int e0 = blockIdx.x * EPB;
    int mybin[8], myrank[8], mypack[8];
#pragma unroll
    for (int j = 0; j < 8; ++j) {
        int e = e0 + j * 1024 + t;
        if (e < N_EDGES) {
            int d = dst[e];
            int bin = d >> 6;
            mybin[j] = bin;
            mypack[j] = (src[e] << 6) | (d & 63);
            myrank[j] = atomicAdd(&hist[bin], 1);
        } else {
            mybin[j] = -1;
        }
    }
    __syncthreads();
    for (int i = t; i < NBINS; i += 1024) base[i] = atomicAdd(&binfill[i], hist[i]);
    __syncthreads();
#pragma unroll
    for (int j = 0; j < 8; ++j) {
        if (mybin[j] >= 0) {
            int bin = mybin[j];
            int pos = base[bin] + myrank[j];
            if (pos < CAP) pairs[bin * CAP + pos] = mypack[j];
        }
    }
}

// ---------------- bin solve ----------------

__global__ __launch_bounds__(256) void k_binsolve(const int* __restrict__ pairs, const int* __restrict__ binfill,
                                                  u16* __restrict__ srt, int* __restrict__ rowbeg,
                                                  int* __restrict__ degA, int* __restrict__ order) {
    __shared__ int lcnt[64];
    __shared__ int lptr[64];
    __shared__ int lcur[64];
    __shared__ int h8[8];
    __shared__ int bb[8];
    int bin = blockIdx.x;
    int t = threadIdx.x;
    int p0 = bin * CAP;
    int cnt = min(binfill[bin], CAP);
    if (t < 64) lcnt[t] = 0;
    if (t < 8) h8[t] = 0;
    __syncthreads();
    for (int i = t; i < cnt; i += 256) atomicAdd(&lcnt[pairs[p0 + i] & 63], 1);
    __syncthreads();
    if (t < 64) {
        int d = lcnt[t];
        int v = d;
#pragma unroll
        for (int off = 1; off < 64; off <<= 1) {
            int u = __shfl_up(v, off);
            if (t >= off) v += u;
        }
        lptr[t] = v - d;
        lcur[t] = v - d;
    }
    __syncthreads();
    for (int i = t; i < cnt; i += 256) {
        int p = pairs[p0 + i];
        int slot = atomicAdd(&lcur[p & 63], 1);
        srt[p0 + slot] = (u16)(p >> 6);
    }
    int node = bin * 64 + t;
    bool act = (t < 64) && (node < N_NODES);
    int b = 0, r8 = 0;
    if (act) {
        rowbeg[node] = p0 + lptr[t];
        degA[node] = lcnt[t];
        b = bucketof(lcnt[t]);
        r8 = atomicAdd(&h8[b], 1);
    }
    __syncthreads();
    if (t == 0) {
        int r = 0;
#pragma unroll
        for (int i = 0; i < 8; ++i) { bb[i] = r; r += h8[i]; }
    }
    __syncthreads();
    if (act) order[bin * 64 + bb[b] + r8] = node;
}

// ---------------- FUSED layer: fp8 gather (bin of 64 nodes -> LDS f16) + dual MFMA GEMM ----------------
// Gather: 16 groups x 16 lanes; each lane 8 fp8 = 8 B; group covers 128 B row = 2 cache lines.
// Self operand: layer 1 from f32 x (cast f16 on the fly), layer 2 from f16 hh.
// Epilogue: C (f32, optional), Cb16 (f16, optional), Cb8 (fp8, optional).

__global__ __launch_bounds__(256) void k_fused(const u8* __restrict__ X8, const float* __restrict__ Xf,
                                               const f16* __restrict__ Xh16, const u16* __restrict__ srt,
                                               const int* __restrict__ rowbeg, const int* __restrict__ degA,
                                               const int* __restrict__ order, const f16* __restrict__ Wf,
                                               const float* __restrict__ bias,
                                               float* __restrict__ C, f16* __restrict__ Cb16,
                                               u8* __restrict__ Cb8) {
    __shared__ f16 agg[64][136];
    int bin = blockIdx.x;
    int n0 = bin << 6;
    int t = threadIdx.x;
    int g = t >> 4, l16 = t & 15;
    int nvalid = N_NODES - n0; if (nvalid > 64) nvalid = 64;
    const u8* __restrict__ base = X8 + l16 * 8;

#pragma unroll
    for (int p = 0; p < 4; ++p) {
        int rank = p * 16 + g;
        if (rank < nvalid) {
            int node = order[n0 + rank];
            int m = node - n0;
            int beg = rowbeg[node];
            int d = degA[node];
            int end = beg + d;
            f32x2 A0[4], A1[4], A2[4], A3[4];
#pragma unroll
            for (int j = 0; j < 4; ++j) {
                A0[j] = (f32x2){0.f, 0.f}; A1[j] = (f32x2){0.f, 0.f};
                A2[j] = (f32x2){0.f, 0.f}; A3[j] = (f32x2){0.f, 0.f};
            }
            int e = beg;
#define GACC(Ar, w) { Ar[0] += __builtin_amdgcn_cvt_pk_f32_fp8((w).x, false); \
                      Ar[1] += __builtin_amdgcn_cvt_pk_f32_fp8((w).x, true);  \
                      Ar[2] += __builtin_amdgcn_cvt_pk_f32_fp8((w).y, false); \
                      Ar[3] += __builtin_amdgcn_cvt_pk_f32_fp8((w).y, true); }
            for (; e + 4 <= end; e += 4) {
                int s0 = __builtin_nontemporal_load(srt + e);
                int s1 = __builtin_nontemporal_load(srt + e + 1);
                int s2 = __builtin_nontemporal_load(srt + e + 2);
                int s3 = __builtin_nontemporal_load(srt + e + 3);
                uint2 w0 = *(const uint2*)(base + (size_t)s0 * DIM);
                uint2 w1 = *(const uint2*)(base + (size_t)s1 * DIM);
                uint2 w2 = *(const uint2*)(base + (size_t)s2 * DIM);
                uint2 w3 = *(const uint2*)(base + (size_t)s3 * DIM);
                GACC(A0, w0); GACC(A1, w1); GACC(A2, w2); GACC(A3, w3);
            }
            if (e < end)     { uint2 w = *(const uint2*)(base + (size_t)__builtin_nontemporal_load(srt + e) * DIM); GACC(A0, w); }
            if (e + 1 < end) { uint2 w = *(const uint2*)(base + (size_t)__builtin_nontemporal_load(srt + e + 1) * DIM); GACC(A1, w); }
            if (e + 2 < end) { uint2 w = *(const uint2*)(base + (size_t)__builtin_nontemporal_load(srt + e + 2) * DIM); GACC(A2, w); }
#undef GACC
            float inv = 1.0f / fmaxf((float)d, 1.0f);
            f16x8 r;
#pragma unroll
            for (int j = 0; j < 4; ++j) {
                f32x2 s = (A0[j] + A1[j]) + (A2[j] + A3[j]);
                r[j * 2]     = (f16)(s.x * inv);
                r[j * 2 + 1] = (f16)(s.y * inv);
            }
            *(f16x8*)&agg[m][l16 * 8] = r;
        }
    }
    __syncthreads();

    int wave = t >> 6, lane = t & 63;
    int r = lane & 15, gg = lane >> 4;
    int rowloc = wave * 16 + r;
    size_t grow = (size_t)n0 + rowloc;
    size_t growc = (grow < N_NODES) ? grow : (N_NODES - 1);

    f32x4 acc[8];
#pragma unroll
    for (int nt = 0; nt < 8; ++nt) acc[nt] = (f32x4){0.f, 0.f, 0.f, 0.f};

#pragma unroll
    for (int kk = 0; kk < 8; ++kk) {
        f16x8 a;
        if (kk < 4) {
            f16x4 q0 = *(const f16x4*)&agg[rowloc][kk * 32 + gg * 4];
            f16x4 q1 = *(const f16x4*)&agg[rowloc][kk * 32 + gg * 4 + 16];
            a = __builtin_shufflevector(q0, q1, 0, 1, 2, 3, 4, 5, 6, 7);
        } else if (Xf) {
            const float* ar = Xf + growc * DIM + (kk - 4) * 32 + gg * 4;
            float4 u0 = *(const float4*)(ar);
            float4 u1 = *(const float4*)(ar + 16);
            a[0]=(f16)u0.x; a[1]=(f16)u0.y; a[2]=(f16)u0.z; a[3]=(f16)u0.w;
            a[4]=(f16)u1.x; a[5]=(f16)u1.y; a[6]=(f16)u1.z; a[7]=(f16)u1.w;
        } else {
            const f16* ar = Xh16 + growc * DIM + (kk - 4) * 32 + gg * 4;
            f16x4 q0 = *(const f16x4*)(ar);
            f16x4 q1 = *(const f16x4*)(ar + 16);
            a = __builtin_shufflevector(q0, q1, 0, 1, 2, 3, 4, 5, 6, 7);
        }
#pragma unroll
        for (int nt = 0; nt < 8; ++nt) {
            f16x8 b = *(const f16x8*)(Wf + ((size_t)((nt * 8 + kk) * 64 + lane)) * 8);
            acc[nt] = __builtin_amdgcn_mfma_f32_16x16x32_f16(a, b, acc[nt], 0, 0, 0);
        }
    }
    size_t rbase = (size_t)n0 + wave * 16 + gg * 4;
#pragma unroll
    for (int nt = 0; nt < 8; ++nt) {
        int colc = nt * 16 + r;
        float bv = bias[colc];
#pragma unroll
        for (int q = 0; q < 4; ++q) {
            size_t node = rbase + q;
            if (node < N_NODES) {
                float v = fmaxf(acc[nt][q] + bv, 0.f);
                if (C)    C[node * DIM + colc] = v;
                if (Cb16) Cb16[node * DIM + colc] = (f16)v;
                if (Cb8) {
                    int pk = __builtin_amdgcn_cvt_pk_fp8_f32(v, v, 0, false);
                    Cb8[node * DIM + colc] = (u8)(pk & 0xff);
                }
            }
        }
    }
}

// ---------------- launch ----------------

extern "C" void kernel_launch(void* const* d_in, const int* in_sizes, int n_in,
                              void* d_out, int out_size, void* d_ws, size_t ws_size,
                              hipStream_t stream) {
    const float* x   = (const float*)d_in[0];
    const int*   ei  = (const int*)d_in[1];
    const float* W1l = (const float*)d_in[2];
    const float* b1  = (const float*)d_in[3];
    const float* W1r = (const float*)d_in[4];
    const float* W2l = (const float*)d_in[5];
    const float* b2  = (const float*)d_in[6];
    const float* W2r = (const float*)d_in[7];
    float* out = (float*)d_out;

    const int* src = ei;
    const int* dst = ei + N_EDGES;

    char* ws = (char*)d_ws;
    int*  binfill = (int*)(ws + 0);              // 3,128 B (zeroed by prep block 3157)
    int*  degA    = (int*)(ws + 3200);           // 200,000 B
    int*  rowbeg  = (int*)(ws + 203264);         // 200,000 B
    int*  order   = (int*)(ws + 403264);         // 200,000 B
    u16*  srt     = (u16*)(ws + 603264);         // 3,203,072 B -> ends 3,806,336
    u8*   x8      = (u8*)(ws + 3806336);         // 6.4 MB fp8 x -> ends 10,206,336
    f16*  hh      = (f16*)(ws + 10206336);       // 12.8 MB f16 h -> ends 23,006,336
    int*  pairs   = (int*)(ws + 23006336);       // 6,406,144 B -> ends 29,412,480
    u8*   hh8     = (u8*)(ws + 23006336);        // 6.4 MB fp8 h (overlaps pairs; pairs dead after binsolve)
    f16*  Wf1     = (f16*)(ws + 29412480);       // 64 KB frag-order
    f16*  Wf2     = Wf1 + 32768;                 // 64 KB -> ends ~29.54 MB

    dim3 blk(256);
    k_prep<<<dim3(3158), blk, 0, stream>>>(x, x8, W1l, W1r, W2l, W2r, Wf1, Wf2, binfill);
    k_binscat<<<dim3(NSCAT), dim3(1024), 0, stream>>>(src, dst, binfill, pairs);
    k_binsolve<<<dim3(NBINS), blk, 0, stream>>>(pairs, binfill, srt, rowbeg, degA, order);

    // layer 1: h = relu(agg8(x) @ W1l^T + b1 + x @ W1r^T)   -> hh (f16) + hh8 (fp8)
    k_fused<<<dim3(NBINS), blk, 0, stream>>>(x8, x, (const f16*)nullptr, srt, rowbeg, degA, order,
                                             Wf1, b1, (float*)nullptr, hh, hh8);

    // layer 2: out = relu(agg8(h) @ W2l^T + b2 + h @ W2r^T) -> out (f32)
    k_fused<<<dim3(NBINS), blk, 0, stream>>>(hh8, (const float*)nullptr, hh, srt, rowbeg, degA, order,
                                             Wf2, b2, out, (f16*)nullptr, (u8*)nullptr);
}